// Round 8
// baseline (224.069 us; speedup 1.0000x reference)
//
#include <hip/hip_runtime.h>
#include <hip/hip_bf16.h>

// Problem: B=2, T=2048, C=1024, H=16, D=64 causal self-attention fwd.
// All inputs fp32; output fp32. Compute in bf16 MFMA (threshold = 2% of max|ref|).

namespace {

constexpr int TT = 2048;
constexpr int CC = 1024;
constexpr int HH = 16;
constexpr int DD = 64;

using bf16x8 = __attribute__((ext_vector_type(8))) __bf16;
using bf16x4 = __attribute__((ext_vector_type(4))) __bf16;
using f32x4  = __attribute__((ext_vector_type(4))) float;
using us8    = __attribute__((ext_vector_type(8))) unsigned short;

__device__ __forceinline__ unsigned short f2b(float f) {
  unsigned u = __float_as_uint(f);
  u += 0x7fffu + ((u >> 16) & 1u);   // RNE
  return (unsigned short)(u >> 16);
}

// async global->LDS, 16B per lane; LDS dest is wave-uniform base + lane*16
__device__ __forceinline__ void gload16(const void* g, void* l) {
  __builtin_amdgcn_global_load_lds(
      (const __attribute__((address_space(1))) void*)g,
      (__attribute__((address_space(3))) void*)l, 16, 0, 0);
}

#if __has_builtin(__builtin_amdgcn_exp2f)
#define FEXP2 __builtin_amdgcn_exp2f
#else
#define FEXP2 exp2f
#endif

// 1/sqrt(64) * log2(e): softmax computed in exp2 domain
#define SCALE2 0.18033688011112042f

} // namespace

// ---------------- fp32 -> bf16 conversion (vectorized) ----------------
__global__ void k_cvt(const float* __restrict__ in, unsigned short* __restrict__ out, int n4) {
  int i = blockIdx.x * 256 + threadIdx.x;
  if (i >= n4) return;
  float4 v = reinterpret_cast<const float4*>(in)[i];
  ushort4 o;
  o.x = f2b(v.x); o.y = f2b(v.y); o.z = f2b(v.z); o.w = f2b(v.w);
  reinterpret_cast<ushort4*>(out)[i] = o;
}

// ---------------- fused QKV GEMM (unchanged from round 7, verified) ----------------
__global__ __launch_bounds__(256, 3) void k_gemm_qkv(
    const unsigned short* __restrict__ A,    // x bf16 [4096][1024]
    const unsigned short* __restrict__ Wq,
    const unsigned short* __restrict__ Wk,
    const unsigned short* __restrict__ Wv,
    const float* __restrict__ bq,
    const float* __restrict__ bk,
    const float* __restrict__ bv,
    unsigned short* __restrict__ qd,         // [BH][T][D]
    unsigned short* __restrict__ kd,         // [BH][T][D]
    unsigned short* __restrict__ vd)         // [BH][D][T]
{
  __shared__ unsigned short la[128 * 32];    // linear, 8 KB
  __shared__ unsigned short lb[128 * 32];
  const int tid = threadIdx.x;
  const int lane = tid & 63;
  const int wid = tid >> 6;
  const int l15 = lane & 15, lg = lane >> 4;
  const int wm = (wid & 1) * 64, wn = (wid >> 1) * 64;
  const int bm = blockIdx.x;
  const int wsel = blockIdx.y >> 3;          // 0=Q 1=K 2=V
  const int bnl = blockIdx.y & 7;

  const unsigned short* W = (wsel == 0) ? Wq : (wsel == 1) ? Wk : Wv;
  const float* bias = (wsel == 0) ? bq : (wsel == 1) ? bk : bv;

  const int srow = lane >> 2;                // 0..15 within segment
  const int sko  = (lane & 3) * 8;           // k-chunk 0/8/16/24

  f32x4 acc[4][4];
#pragma unroll
  for (int i = 0; i < 4; ++i)
#pragma unroll
    for (int j = 0; j < 4; ++j) acc[i][j] = f32x4{0.f, 0.f, 0.f, 0.f};

  for (int kt = 0; kt < CC / 32; ++kt) {
    __syncthreads();                         // prior frag reads done before overwrite
#pragma unroll
    for (int s = 0; s < 2; ++s) {
      const int seg = wid * 2 + s;           // 0..7 (16 rows each)
      const int row = seg * 16 + srow;
      gload16(&A[(bm * 128 + row) * CC + kt * 32 + sko], &la[seg * 512]);
      gload16(&W[(bnl * 128 + row) * CC + kt * 32 + sko], &lb[seg * 512]);
    }
    __syncthreads();                         // drains vmcnt(0): staged data visible
    bf16x8 af[4], bf[4];
#pragma unroll
    for (int mi = 0; mi < 4; ++mi)
      af[mi] = __builtin_bit_cast(bf16x8,
        *reinterpret_cast<const us8*>(&la[(wm + mi * 16 + l15) * 32 + lg * 8]));
#pragma unroll
    for (int ni = 0; ni < 4; ++ni)
      bf[ni] = __builtin_bit_cast(bf16x8,
        *reinterpret_cast<const us8*>(&lb[(wn + ni * 16 + l15) * 32 + lg * 8]));
#pragma unroll
    for (int mi = 0; mi < 4; ++mi)
#pragma unroll
      for (int ni = 0; ni < 4; ++ni)
        acc[mi][ni] = __builtin_amdgcn_mfma_f32_16x16x32_bf16(af[mi], bf[ni], acc[mi][ni], 0, 0, 0);
  }

  // epilogue: C/D col = lane&15, row = (lane>>4)*4 + r
#pragma unroll
  for (int ni = 0; ni < 4; ++ni) {
    const int nl = bnl * 128 + wn + ni * 16 + l15;   // 0..1023
    const float bvl = bias[nl];
    const int hh = nl >> 6, d = nl & (DD - 1);
#pragma unroll
    for (int mi = 0; mi < 4; ++mi) {
#pragma unroll
      for (int r = 0; r < 4; ++r) {
        const int m = bm * 128 + wm + mi * 16 + lg * 4 + r;
        const unsigned short bb = f2b(acc[mi][ni][r] + bvl);
        const int b = m >> 11, t = m & (TT - 1);
        if (wsel == 0)
          qd[((b * HH + hh) * TT + t) * DD + d] = bb;
        else if (wsel == 1)
          kd[((b * HH + hh) * TT + t) * DD + d] = bb;
        else
          vd[((b * HH + hh) * DD + d) * TT + t] = bb;
      }
    }
  }
}

// ---------------- output projection GEMM (unchanged from round 7, verified) ----------------
__global__ __launch_bounds__(256, 2) void k_gemm_o(
    const unsigned short* __restrict__ A,    // y bf16 [4096][1024]
    const unsigned short* __restrict__ W,    // Wo bf16 [1024][1024]
    const float* __restrict__ bias,
    float* __restrict__ out)
{
  __shared__ unsigned short la[128 * 32];
  __shared__ unsigned short lb[64 * 32];
  const int tid = threadIdx.x;
  const int lane = tid & 63;
  const int wid = tid >> 6;
  const int l15 = lane & 15, lg = lane >> 4;
  const int wm = (wid & 1) * 64, wn = (wid >> 1) * 32;
  const int bm = blockIdx.x, bn = blockIdx.y;

  const int srow = lane >> 2;
  const int sko  = (lane & 3) * 8;

  f32x4 acc[4][2];
#pragma unroll
  for (int i = 0; i < 4; ++i)
#pragma unroll
    for (int j = 0; j < 2; ++j) acc[i][j] = f32x4{0.f, 0.f, 0.f, 0.f};

  for (int kt = 0; kt < CC / 32; ++kt) {
    __syncthreads();
#pragma unroll
    for (int s = 0; s < 2; ++s) {
      const int seg = wid * 2 + s;
      gload16(&A[(bm * 128 + seg * 16 + srow) * CC + kt * 32 + sko], &la[seg * 512]);
    }
    gload16(&W[(bn * 64 + wid * 16 + srow) * CC + kt * 32 + sko], &lb[wid * 512]);
    __syncthreads();
    bf16x8 af[4], bf[2];
#pragma unroll
    for (int mi = 0; mi < 4; ++mi)
      af[mi] = __builtin_bit_cast(bf16x8,
        *reinterpret_cast<const us8*>(&la[(wm + mi * 16 + l15) * 32 + lg * 8]));
#pragma unroll
    for (int ni = 0; ni < 2; ++ni)
      bf[ni] = __builtin_bit_cast(bf16x8,
        *reinterpret_cast<const us8*>(&lb[(wn + ni * 16 + l15) * 32 + lg * 8]));
#pragma unroll
    for (int mi = 0; mi < 4; ++mi)
#pragma unroll
      for (int ni = 0; ni < 2; ++ni)
        acc[mi][ni] = __builtin_amdgcn_mfma_f32_16x16x32_bf16(af[mi], bf[ni], acc[mi][ni], 0, 0, 0);
  }

#pragma unroll
  for (int ni = 0; ni < 2; ++ni) {
    const int n = bn * 64 + wn + ni * 16 + l15;
    const float bvl = bias[n];
#pragma unroll
    for (int mi = 0; mi < 4; ++mi)
#pragma unroll
      for (int r = 0; r < 4; ++r) {
        const int m = bm * 128 + wm + mi * 16 + lg * 4 + r;
        out[m * CC + n] = acc[mi][ni][r] + bvl;
      }
  }
}

// ---------------- flash attention v3 ----------------
// 2 waves/block (128 thr), grid (32,32) -> 2048 waves = 2 waves/SIMD.
// Wave w handles key-tiles kt ≡ w (mod 2) for BOTH sets of the q-pair (p, 63-p),
// building partial (m,l,o); partials merged in-block via LDS at the end.
// processSet internals identical to the verified round-6/7 kernel.
__global__ __launch_bounds__(128) void k_attn(
    const unsigned short* __restrict__ Q,   // [BH][T][D] bf16
    const unsigned short* __restrict__ K,   // [BH][T][D] bf16
    const unsigned short* __restrict__ VT,  // [BH][D][T] bf16
    unsigned short* __restrict__ Y)         // [B][T][C] bf16
{
  __shared__ unsigned short pl[2][2][2][16][80];  // [wave][set][qi][q-row][key], 20 KB
  const int tid = threadIdx.x;
  const int lane = tid & 63;
  const int wid = tid >> 6;               // 0/1 = key parity
  const int l15 = lane & 15, lg = lane >> 4;
  const int bh = blockIdx.y;
  const int b = bh >> 4, h = bh & 15;
  const int p = blockIdx.x;                // 0..31
  const int qb0A = p * 32;                 // low q-block
  const int qb0B = (63 - p) * 32;          // high q-block
  const int nktA = (qb0A + 95) >> 6;
  const int nktB = (qb0B + 95) >> 6;       // nktA + nktB == 33 for all p

  const unsigned short* Qh = Q + bh * TT * DD;
  const unsigned short* Kh = K + bh * TT * DD;
  const unsigned short* Vh = VT + bh * DD * TT;

  auto ldq = [&](bf16x8 (&qf)[2][2], int qb0) {
#pragma unroll
    for (int qi = 0; qi < 2; ++qi)
#pragma unroll
      for (int kk = 0; kk < 2; ++kk)
        qf[qi][kk] = __builtin_bit_cast(bf16x8,
          *reinterpret_cast<const us8*>(&Qh[(qb0 + qi * 16 + l15) * DD + kk * 32 + lg * 8]));
  };
  auto ldk = [&](bf16x8 (&kf)[4][2], int kb) {
#pragma unroll
    for (int f = 0; f < 4; ++f)
#pragma unroll
      for (int kk = 0; kk < 2; ++kk)
        kf[f][kk] = __builtin_bit_cast(bf16x8,
          *reinterpret_cast<const us8*>(&Kh[(kb + f * 16 + l15) * DD + kk * 32 + lg * 8]));
  };
  auto ldv = [&](bf16x8 (&vf)[2][4], int kb) {
#pragma unroll
    for (int kk = 0; kk < 2; ++kk)
#pragma unroll
      for (int dc = 0; dc < 4; ++dc)
        vf[kk][dc] = __builtin_bit_cast(bf16x8,
          *reinterpret_cast<const us8*>(&Vh[(dc * 16 + l15) * TT + kb + kk * 32 + lg * 8]));
  };

  bf16x8 qfA[2][2], qfB[2][2];
  ldq(qfA, qb0A); ldq(qfB, qb0B);

  f32x4 oA[2][4], oB[2][4];
  float mrA[2], lrA[2], mrB[2], lrB[2];
#pragma unroll
  for (int qi = 0; qi < 2; ++qi) {
    mrA[qi] = -INFINITY; lrA[qi] = 0.f;
    mrB[qi] = -INFINITY; lrB[qi] = 0.f;
#pragma unroll
    for (int dc = 0; dc < 4; ++dc) {
      oA[qi][dc] = f32x4{0.f, 0.f, 0.f, 0.f};
      oB[qi][dc] = f32x4{0.f, 0.f, 0.f, 0.f};
    }
  }

  auto processSet = [&](const int qb0, const bf16x8 (&qf)[2][2], f32x4 (&o)[2][4],
                        float (&mr)[2], float (&lr)[2],
                        unsigned short (&plS)[2][16][80],
                        const bf16x8 (&kf)[4][2], const bf16x8 (&vf)[2][4],
                        const int kbase) {
    // S^T = K Q^T : C[row=key=lg*4+r][col=q=l15]
    f32x4 s[2][4];
#pragma unroll
    for (int qi = 0; qi < 2; ++qi)
#pragma unroll
      for (int f = 0; f < 4; ++f) {
        f32x4 t0 = __builtin_amdgcn_mfma_f32_16x16x32_bf16(kf[f][0], qf[qi][0],
                                                           f32x4{0.f,0.f,0.f,0.f}, 0, 0, 0);
        s[qi][f] = __builtin_amdgcn_mfma_f32_16x16x32_bf16(kf[f][1], qf[qi][1], t0, 0, 0, 0);
      }
    const bool needMask = (kbase + 63 > qb0);  // wave-uniform
#pragma unroll
    for (int qi = 0; qi < 2; ++qi) {
      const int qg = qb0 + qi * 16 + l15;
      float sv[4][4];
      float mt = -INFINITY;
#pragma unroll
      for (int f = 0; f < 4; ++f)
#pragma unroll
        for (int r = 0; r < 4; ++r) {
          float v = s[qi][f][r] * SCALE2;
          if (needMask) v = (kbase + f * 16 + lg * 4 + r <= qg) ? v : -INFINITY;
          sv[f][r] = v;
          mt = fmaxf(mt, v);
        }
      mt = fmaxf(mt, __shfl_xor(mt, 16));
      mt = fmaxf(mt, __shfl_xor(mt, 32));
      const float mn = fmaxf(mr[qi], mt);
      const float al = FEXP2(mr[qi] - mn);   // first tile: exp2(-inf)=0
      mr[qi] = mn;
      float rs = 0.f;
#pragma unroll
      for (int f = 0; f < 4; ++f) {
        const float p0 = FEXP2(sv[f][0] - mn), p1 = FEXP2(sv[f][1] - mn);
        const float p2 = FEXP2(sv[f][2] - mn), p3 = FEXP2(sv[f][3] - mn);
        rs += (p0 + p1) + (p2 + p3);
        bf16x4 pk;
        pk[0] = (__bf16)p0; pk[1] = (__bf16)p1; pk[2] = (__bf16)p2; pk[3] = (__bf16)p3;
        *reinterpret_cast<bf16x4*>(&plS[qi][l15][f * 16 + lg * 4]) = pk;  // keys contiguous
      }
      rs += __shfl_xor(rs, 16);
      rs += __shfl_xor(rs, 32);
      lr[qi] = lr[qi] * al + rs;
      float alr[4];
#pragma unroll
      for (int r = 0; r < 4; ++r) alr[r] = __shfl(al, lg * 4 + r);  // q remap for C-layout
#pragma unroll
      for (int dc = 0; dc < 4; ++dc)
#pragma unroll
        for (int r = 0; r < 4; ++r) o[qi][dc][r] *= alr[r];
    }
    asm volatile("s_waitcnt lgkmcnt(0)" ::: "memory");
    __builtin_amdgcn_sched_barrier(0);
    // PV: A = P[row=q][k=key] from LDS, B = V^T fragments
#pragma unroll
    for (int qi = 0; qi < 2; ++qi) {
      const bf16x8 pa0 = __builtin_bit_cast(bf16x8,
        *reinterpret_cast<const us8*>(&plS[qi][l15][lg * 8]));
      const bf16x8 pa1 = __builtin_bit_cast(bf16x8,
        *reinterpret_cast<const us8*>(&plS[qi][l15][32 + lg * 8]));
#pragma unroll
      for (int dc = 0; dc < 4; ++dc) {
        o[qi][dc] = __builtin_amdgcn_mfma_f32_16x16x32_bf16(pa0, vf[0][dc], o[qi][dc], 0, 0, 0);
        o[qi][dc] = __builtin_amdgcn_mfma_f32_16x16x32_bf16(pa1, vf[1][dc], o[qi][dc], 0, 0, 0);
      }
    }
  };

  // main loop: this wave's parity of key tiles, shared K/V fragments for both sets
  for (int kt = wid; kt < nktB; kt += 2) {
    const int kbase = kt * 64;
    bf16x8 kf[4][2], vf[2][4];
    ldk(kf, kbase);
    ldv(vf, kbase);
    processSet(qb0B, qfB, oB, mrB, lrB, pl[wid][0], kf, vf, kbase);
    if (kt < nktA)
      processSet(qb0A, qfA, oA, mrA, lrA, pl[wid][1], kf, vf, kbase);
  }

  // ---- cross-wave merge of partials (LDS reused; pl dead after sync) ----
  float* ex = reinterpret_cast<float*>(pl);     // ex[set][lane][36] floats
  auto writeState = [&](float* dst, const f32x4 (&o)[2][4],
                        const float (&mr)[2], const float (&lr)[2]) {
    float* q = dst + lane * 36;
#pragma unroll
    for (int qi = 0; qi < 2; ++qi)
#pragma unroll
      for (int dc = 0; dc < 4; ++dc)
        *reinterpret_cast<f32x4*>(q + qi * 16 + dc * 4) = o[qi][dc];
    q[32] = mr[0]; q[33] = mr[1]; q[34] = lr[0]; q[35] = lr[1];
  };
  auto mergeWrite = [&](int qb0, const f32x4 (&o)[2][4],
                        const float (&mr)[2], const float (&lr)[2],
                        const float* srcBase) {
    const float* q = srcBase + lane * 36;
#pragma unroll
    for (int qi = 0; qi < 2; ++qi) {
      const float m1 = q[32 + qi], l1 = q[34 + qi];
      const float m = fmaxf(mr[qi], m1);
      const float a0 = FEXP2(mr[qi] - m), a1 = FEXP2(m1 - m);
      const float l = lr[qi] * a0 + l1 * a1;
      float a0r[4], a1r[4], linv[4];
#pragma unroll
      for (int r = 0; r < 4; ++r) {
        a0r[r] = __shfl(a0, lg * 4 + r);
        a1r[r] = __shfl(a1, lg * 4 + r);
        linv[r] = 1.f / __shfl(l, lg * 4 + r);
      }
#pragma unroll
      for (int dc = 0; dc < 4; ++dc) {
        const f32x4 o1 = *reinterpret_cast<const f32x4*>(q + qi * 16 + dc * 4);
#pragma unroll
        for (int r = 0; r < 4; ++r) {
          const int t = qb0 + qi * 16 + lg * 4 + r;
          Y[(b * TT + t) * CC + h * DD + dc * 16 + l15] =
              f2b((o[qi][dc][r] * a0r[r] + o1[r] * a1r[r]) * linv[r]);
        }
      }
    }
  };

  __syncthreads();                               // all PV done; pl dead
  if (wid == 1) writeState(ex,            oB, mrB, lrB);   // wave1's B partial
  else          writeState(ex + 64 * 36,  oA, mrA, lrA);   // wave0's A partial
  __syncthreads();
  if (wid == 0) mergeWrite(qb0B, oB, mrB, lrB, ex);            // wave0 merges B
  else          mergeWrite(qb0A, oA, mrA, lrA, ex + 64 * 36);  // wave1 merges A
}

extern "C" void kernel_launch(void* const* d_in, const int* in_sizes, int n_in,
                              void* d_out, int out_size, void* d_ws, size_t ws_size,
                              hipStream_t stream) {
  const float* x  = (const float*)d_in[0];
  const float* Wq = (const float*)d_in[1];
  const float* bq = (const float*)d_in[2];
  const float* Wk = (const float*)d_in[3];
  const float* bk = (const float*)d_in[4];
  const float* Wv = (const float*)d_in[5];
  const float* bv = (const float*)d_in[6];
  const float* Wo = (const float*)d_in[7];
  const float* bo = (const float*)d_in[8];
  float* out = (float*)d_out;

  unsigned short* ws  = (unsigned short*)d_ws;
  unsigned short* xb  = ws;               // x bf16       [4096][1024]
  unsigned short* wqb = xb  + 4194304;    // Wq bf16
  unsigned short* wkb = wqb + 1048576;
  unsigned short* wvb = wkb + 1048576;
  unsigned short* wob = wvb + 1048576;
  unsigned short* qb  = wob + 1048576;    // Q  [BH][T][D]
  unsigned short* kb  = qb  + 4194304;    // K  [BH][T][D]
  unsigned short* vt  = kb  + 4194304;    // V^T [BH][D][T]
  unsigned short* yb  = xb;               // attn out [B][T][C] — aliases xb (dead after QKV GEMM)

  k_cvt<<<4096, 256, 0, stream>>>(x,  xb,  1048576);
  k_cvt<<<1024, 256, 0, stream>>>(Wq, wqb, 262144);
  k_cvt<<<1024, 256, 0, stream>>>(Wk, wkb, 262144);
  k_cvt<<<1024, 256, 0, stream>>>(Wv, wvb, 262144);
  k_cvt<<<1024, 256, 0, stream>>>(Wo, wob, 262144);

  k_gemm_qkv<<<dim3(32, 24), 256, 0, stream>>>(xb, wqb, wkb, wvb, bq, bk, bv, qb, kb, vt);

  k_attn<<<dim3(32, 32), 128, 0, stream>>>(qb, kb, vt, yb);

  k_gemm_o<<<dim3(32, 16), 256, 0, stream>>>(yb, wob, bo, out);
}

// Round 9
// 214.542 us; speedup vs baseline: 1.0444x; 1.0444x over previous
//
#include <hip/hip_runtime.h>
#include <hip/hip_bf16.h>

// Problem: B=2, T=2048, C=1024, H=16, D=64 causal self-attention fwd.
// All inputs fp32; output fp32. Compute in bf16 MFMA (threshold = 2% of max|ref|).

namespace {

constexpr int TT = 2048;
constexpr int CC = 1024;
constexpr int HH = 16;
constexpr int DD = 64;

using bf16x8 = __attribute__((ext_vector_type(8))) __bf16;
using bf16x4 = __attribute__((ext_vector_type(4))) __bf16;
using f32x4  = __attribute__((ext_vector_type(4))) float;
using us8    = __attribute__((ext_vector_type(8))) unsigned short;

__device__ __forceinline__ unsigned short f2b(float f) {
  unsigned u = __float_as_uint(f);
  u += 0x7fffu + ((u >> 16) & 1u);   // RNE
  return (unsigned short)(u >> 16);
}

// async global->LDS, 16B per lane; LDS dest is wave-uniform base + lane*16
__device__ __forceinline__ void gload16(const void* g, void* l) {
  __builtin_amdgcn_global_load_lds(
      (const __attribute__((address_space(1))) void*)g,
      (__attribute__((address_space(3))) void*)l, 16, 0, 0);
}

#if __has_builtin(__builtin_amdgcn_exp2f)
#define FEXP2 __builtin_amdgcn_exp2f
#else
#define FEXP2 exp2f
#endif

// 1/sqrt(64) * log2(e): softmax computed in exp2 domain
#define SCALE2 0.18033688011112042f

} // namespace

// ---------------- fp32 -> bf16 conversion: all 5 tensors in ONE launch ----------------
// dst = ws, laid out contiguously as [xb | wqb | wkb | wvb | wob] (ushort),
// matching float4-index ranges below.
__global__ void k_cvt_all(const float* __restrict__ x,
                          const float* __restrict__ wq, const float* __restrict__ wk,
                          const float* __restrict__ wv, const float* __restrict__ wo,
                          unsigned short* __restrict__ dst) {
  const int i = blockIdx.x * 256 + threadIdx.x;   // 0 .. 2097151 float4s
  const float* src; int off;
  if (i < 1048576)      { src = x;  off = i; }
  else if (i < 1310720) { src = wq; off = i - 1048576; }
  else if (i < 1572864) { src = wk; off = i - 1310720; }
  else if (i < 1835008) { src = wv; off = i - 1572864; }
  else                  { src = wo; off = i - 1835008; }
  float4 v = reinterpret_cast<const float4*>(src)[off];
  ushort4 o;
  o.x = f2b(v.x); o.y = f2b(v.y); o.z = f2b(v.z); o.w = f2b(v.w);
  reinterpret_cast<ushort4*>(dst)[i] = o;
}

// ---------------- fused QKV GEMM, 2-phase double-buffered staging ----------------
// out[m,n] = sum_k x[m,k]*W[n,k] + bias[n] for W in {Wq,Wk,Wv} selected by blockIdx.y>>3.
// 128x128 tile, BK=32. T3 minimal 2-phase: STAGE(next) before compute(cur),
// one vmcnt(0)+barrier per K-step. grid (32,24) = 768 blocks -> 3 blocks/CU.
__global__ __launch_bounds__(256, 3) void k_gemm_qkv(
    const unsigned short* __restrict__ A,    // x bf16 [4096][1024]
    const unsigned short* __restrict__ Wq,
    const unsigned short* __restrict__ Wk,
    const unsigned short* __restrict__ Wv,
    const float* __restrict__ bq,
    const float* __restrict__ bk,
    const float* __restrict__ bv,
    unsigned short* __restrict__ qd,         // [BH][T][D]
    unsigned short* __restrict__ kd,         // [BH][T][D]
    unsigned short* __restrict__ vd)         // [BH][D][T]
{
  __shared__ unsigned short la[2][128 * 32];   // 2 x 8 KB
  __shared__ unsigned short lb[2][128 * 32];
  const int tid = threadIdx.x;
  const int lane = tid & 63;
  const int wid = tid >> 6;
  const int l15 = lane & 15, lg = lane >> 4;
  const int wm = (wid & 1) * 64, wn = (wid >> 1) * 64;
  const int bm = blockIdx.x;
  const int wsel = blockIdx.y >> 3;          // 0=Q 1=K 2=V
  const int bnl = blockIdx.y & 7;

  const unsigned short* W = (wsel == 0) ? Wq : (wsel == 1) ? Wk : Wv;
  const float* bias = (wsel == 0) ? bq : (wsel == 1) ? bk : bv;

  const int srow = lane >> 2;                // 0..15 within segment
  const int sko  = (lane & 3) * 8;           // k-chunk 0/8/16/24

  auto STAGE = [&](int buf, int kt) {
#pragma unroll
    for (int s = 0; s < 2; ++s) {
      const int seg = wid * 2 + s;           // 0..7 (16 rows each)
      const int row = seg * 16 + srow;
      gload16(&A[(bm * 128 + row) * CC + kt * 32 + sko], &la[buf][seg * 512]);
      gload16(&W[(bnl * 128 + row) * CC + kt * 32 + sko], &lb[buf][seg * 512]);
    }
  };

  f32x4 acc[4][4];
#pragma unroll
  for (int i = 0; i < 4; ++i)
#pragma unroll
    for (int j = 0; j < 4; ++j) acc[i][j] = f32x4{0.f, 0.f, 0.f, 0.f};

  STAGE(0, 0);
  asm volatile("s_waitcnt vmcnt(0)" ::: "memory");
  __syncthreads();

  int cur = 0;
  for (int kt = 0; kt < CC / 32; ++kt) {
    if (kt + 1 < CC / 32) STAGE(cur ^ 1, kt + 1);   // prefetch flies under MFMA
    bf16x8 af[4], bf[4];
#pragma unroll
    for (int mi = 0; mi < 4; ++mi)
      af[mi] = __builtin_bit_cast(bf16x8,
        *reinterpret_cast<const us8*>(&la[cur][(wm + mi * 16 + l15) * 32 + lg * 8]));
#pragma unroll
    for (int ni = 0; ni < 4; ++ni)
      bf[ni] = __builtin_bit_cast(bf16x8,
        *reinterpret_cast<const us8*>(&lb[cur][(wn + ni * 16 + l15) * 32 + lg * 8]));
#pragma unroll
    for (int mi = 0; mi < 4; ++mi)
#pragma unroll
      for (int ni = 0; ni < 4; ++ni)
        acc[mi][ni] = __builtin_amdgcn_mfma_f32_16x16x32_bf16(af[mi], bf[ni], acc[mi][ni], 0, 0, 0);
    asm volatile("s_waitcnt vmcnt(0)" ::: "memory");  // next tile landed
    __syncthreads();                                  // all waves done reading cur
    cur ^= 1;
  }

  // epilogue: C/D col = lane&15, row = (lane>>4)*4 + r
#pragma unroll
  for (int ni = 0; ni < 4; ++ni) {
    const int nl = bnl * 128 + wn + ni * 16 + l15;   // 0..1023
    const float bvl = bias[nl];
    const int hh = nl >> 6, d = nl & (DD - 1);
#pragma unroll
    for (int mi = 0; mi < 4; ++mi) {
#pragma unroll
      for (int r = 0; r < 4; ++r) {
        const int m = bm * 128 + wm + mi * 16 + lg * 4 + r;
        const unsigned short bb = f2b(acc[mi][ni][r] + bvl);
        const int b = m >> 11, t = m & (TT - 1);
        if (wsel == 0)
          qd[((b * HH + hh) * TT + t) * DD + d] = bb;
        else if (wsel == 1)
          kd[((b * HH + hh) * TT + t) * DD + d] = bb;
        else
          vd[((b * HH + hh) * DD + d) * TT + t] = bb;
      }
    }
  }
}

// ---------------- output projection GEMM, 2-phase double-buffered ----------------
// 128x64 tile, BK=32, grid (32,16) = 512 blocks -> 2 blocks/CU.
__global__ __launch_bounds__(256, 2) void k_gemm_o(
    const unsigned short* __restrict__ A,    // y bf16 [4096][1024]
    const unsigned short* __restrict__ W,    // Wo bf16 [1024][1024]
    const float* __restrict__ bias,
    float* __restrict__ out)
{
  __shared__ unsigned short la[2][128 * 32];
  __shared__ unsigned short lb[2][64 * 32];
  const int tid = threadIdx.x;
  const int lane = tid & 63;
  const int wid = tid >> 6;
  const int l15 = lane & 15, lg = lane >> 4;
  const int wm = (wid & 1) * 64, wn = (wid >> 1) * 32;
  const int bm = blockIdx.x, bn = blockIdx.y;

  const int srow = lane >> 2;
  const int sko  = (lane & 3) * 8;

  auto STAGE = [&](int buf, int kt) {
#pragma unroll
    for (int s = 0; s < 2; ++s) {
      const int seg = wid * 2 + s;
      gload16(&A[(bm * 128 + seg * 16 + srow) * CC + kt * 32 + sko], &la[buf][seg * 512]);
    }
    gload16(&W[(bn * 64 + wid * 16 + srow) * CC + kt * 32 + sko], &lb[buf][wid * 512]);
  };

  f32x4 acc[4][2];
#pragma unroll
  for (int i = 0; i < 4; ++i)
#pragma unroll
    for (int j = 0; j < 2; ++j) acc[i][j] = f32x4{0.f, 0.f, 0.f, 0.f};

  STAGE(0, 0);
  asm volatile("s_waitcnt vmcnt(0)" ::: "memory");
  __syncthreads();

  int cur = 0;
  for (int kt = 0; kt < CC / 32; ++kt) {
    if (kt + 1 < CC / 32) STAGE(cur ^ 1, kt + 1);
    bf16x8 af[4], bf[2];
#pragma unroll
    for (int mi = 0; mi < 4; ++mi)
      af[mi] = __builtin_bit_cast(bf16x8,
        *reinterpret_cast<const us8*>(&la[cur][(wm + mi * 16 + l15) * 32 + lg * 8]));
#pragma unroll
    for (int ni = 0; ni < 2; ++ni)
      bf[ni] = __builtin_bit_cast(bf16x8,
        *reinterpret_cast<const us8*>(&lb[cur][(wn + ni * 16 + l15) * 32 + lg * 8]));
#pragma unroll
    for (int mi = 0; mi < 4; ++mi)
#pragma unroll
      for (int ni = 0; ni < 2; ++ni)
        acc[mi][ni] = __builtin_amdgcn_mfma_f32_16x16x32_bf16(af[mi], bf[ni], acc[mi][ni], 0, 0, 0);
    asm volatile("s_waitcnt vmcnt(0)" ::: "memory");
    __syncthreads();
    cur ^= 1;
  }

#pragma unroll
  for (int ni = 0; ni < 2; ++ni) {
    const int n = bn * 64 + wn + ni * 16 + l15;
    const float bvl = bias[n];
#pragma unroll
    for (int mi = 0; mi < 4; ++mi)
#pragma unroll
      for (int r = 0; r < 4; ++r) {
        const int m = bm * 128 + wm + mi * 16 + lg * 4 + r;
        out[m * CC + n] = acc[mi][ni][r] + bvl;
      }
  }
}

// ---------------- flash attention (exact round-7 verified version) ----------------
// 1 wave/block; each wave owns the q-block PAIR (p, 63-p) -> uniform 33 k-tiles/wave.
// Swapped QK^T (mfma(K,Q)): lane holds 16 key-scores of ONE query column ->
// softmax reduce = in-lane chain + 2 shfl; K/V fragment loads shared by both sets.
__global__ __launch_bounds__(64) void k_attn(
    const unsigned short* __restrict__ Q,   // [BH][T][D] bf16
    const unsigned short* __restrict__ K,   // [BH][T][D] bf16
    const unsigned short* __restrict__ VT,  // [BH][D][T] bf16
    unsigned short* __restrict__ Y)         // [B][T][C] bf16
{
  __shared__ unsigned short pl[2][2][16][80];  // [set][qi][q-row][key], padded rows
  const int lane = threadIdx.x;
  const int l15 = lane & 15, lg = lane >> 4;
  const int bh = blockIdx.y;
  const int b = bh >> 4, h = bh & 15;
  const int p = blockIdx.x;                // 0..31
  const int qb0A = p * 32;                 // low q-block
  const int qb0B = (63 - p) * 32;          // high q-block
  const int nktA = (qb0A + 95) >> 6;
  const int nktB = (qb0B + 95) >> 6;       // nktA + nktB == 33 for all p

  const unsigned short* Qh = Q + bh * TT * DD;
  const unsigned short* Kh = K + bh * TT * DD;
  const unsigned short* Vh = VT + bh * DD * TT;

  auto ldq = [&](bf16x8 (&qf)[2][2], int qb0) {
#pragma unroll
    for (int qi = 0; qi < 2; ++qi)
#pragma unroll
      for (int kk = 0; kk < 2; ++kk)
        qf[qi][kk] = __builtin_bit_cast(bf16x8,
          *reinterpret_cast<const us8*>(&Qh[(qb0 + qi * 16 + l15) * DD + kk * 32 + lg * 8]));
  };
  auto ldk = [&](bf16x8 (&kf)[4][2], int kb) {
#pragma unroll
    for (int f = 0; f < 4; ++f)
#pragma unroll
      for (int kk = 0; kk < 2; ++kk)
        kf[f][kk] = __builtin_bit_cast(bf16x8,
          *reinterpret_cast<const us8*>(&Kh[(kb + f * 16 + l15) * DD + kk * 32 + lg * 8]));
  };
  auto ldv = [&](bf16x8 (&vf)[2][4], int kb) {
#pragma unroll
    for (int kk = 0; kk < 2; ++kk)
#pragma unroll
      for (int dc = 0; dc < 4; ++dc)
        vf[kk][dc] = __builtin_bit_cast(bf16x8,
          *reinterpret_cast<const us8*>(&Vh[(dc * 16 + l15) * TT + kb + kk * 32 + lg * 8]));
  };

  bf16x8 qfA[2][2], qfB[2][2];
  ldq(qfA, qb0A); ldq(qfB, qb0B);

  f32x4 oA[2][4], oB[2][4];
  float mrA[2], lrA[2], mrB[2], lrB[2];
#pragma unroll
  for (int qi = 0; qi < 2; ++qi) {
    mrA[qi] = -INFINITY; lrA[qi] = 0.f;
    mrB[qi] = -INFINITY; lrB[qi] = 0.f;
#pragma unroll
    for (int dc = 0; dc < 4; ++dc) {
      oA[qi][dc] = f32x4{0.f, 0.f, 0.f, 0.f};
      oB[qi][dc] = f32x4{0.f, 0.f, 0.f, 0.f};
    }
  }

  auto processSet = [&](const int qb0, const bf16x8 (&qf)[2][2], f32x4 (&o)[2][4],
                        float (&mr)[2], float (&lr)[2],
                        unsigned short (&plS)[2][16][80],
                        const bf16x8 (&kf)[4][2], const bf16x8 (&vf)[2][4],
                        const int kbase) {
    // S^T = K Q^T : C[row=key=lg*4+r][col=q=l15]
    f32x4 s[2][4];
#pragma unroll
    for (int qi = 0; qi < 2; ++qi)
#pragma unroll
      for (int f = 0; f < 4; ++f) {
        f32x4 t0 = __builtin_amdgcn_mfma_f32_16x16x32_bf16(kf[f][0], qf[qi][0],
                                                           f32x4{0.f,0.f,0.f,0.f}, 0, 0, 0);
        s[qi][f] = __builtin_amdgcn_mfma_f32_16x16x32_bf16(kf[f][1], qf[qi][1], t0, 0, 0, 0);
      }
    const bool needMask = (kbase + 63 > qb0);  // wave-uniform
#pragma unroll
    for (int qi = 0; qi < 2; ++qi) {
      const int qg = qb0 + qi * 16 + l15;
      float sv[4][4];
      float mt = -INFINITY;
#pragma unroll
      for (int f = 0; f < 4; ++f)
#pragma unroll
        for (int r = 0; r < 4; ++r) {
          float v = s[qi][f][r] * SCALE2;
          if (needMask) v = (kbase + f * 16 + lg * 4 + r <= qg) ? v : -INFINITY;
          sv[f][r] = v;
          mt = fmaxf(mt, v);
        }
      mt = fmaxf(mt, __shfl_xor(mt, 16));
      mt = fmaxf(mt, __shfl_xor(mt, 32));
      const float mn = fmaxf(mr[qi], mt);
      const float al = FEXP2(mr[qi] - mn);   // first tile: exp2(-inf)=0
      mr[qi] = mn;
      float rs = 0.f;
#pragma unroll
      for (int f = 0; f < 4; ++f) {
        const float p0 = FEXP2(sv[f][0] - mn), p1 = FEXP2(sv[f][1] - mn);
        const float p2 = FEXP2(sv[f][2] - mn), p3 = FEXP2(sv[f][3] - mn);
        rs += (p0 + p1) + (p2 + p3);
        bf16x4 pk;
        pk[0] = (__bf16)p0; pk[1] = (__bf16)p1; pk[2] = (__bf16)p2; pk[3] = (__bf16)p3;
        *reinterpret_cast<bf16x4*>(&plS[qi][l15][f * 16 + lg * 4]) = pk;  // keys contiguous
      }
      rs += __shfl_xor(rs, 16);
      rs += __shfl_xor(rs, 32);
      lr[qi] = lr[qi] * al + rs;
      float alr[4];
#pragma unroll
      for (int r = 0; r < 4; ++r) alr[r] = __shfl(al, lg * 4 + r);  // q remap for C-layout
#pragma unroll
      for (int dc = 0; dc < 4; ++dc)
#pragma unroll
        for (int r = 0; r < 4; ++r) o[qi][dc][r] *= alr[r];
    }
    asm volatile("s_waitcnt lgkmcnt(0)" ::: "memory");
    __builtin_amdgcn_sched_barrier(0);
    // PV: A = P[row=q][k=key] from LDS, B = V^T fragments
#pragma unroll
    for (int qi = 0; qi < 2; ++qi) {
      const bf16x8 pa0 = __builtin_bit_cast(bf16x8,
        *reinterpret_cast<const us8*>(&plS[qi][l15][lg * 8]));
      const bf16x8 pa1 = __builtin_bit_cast(bf16x8,
        *reinterpret_cast<const us8*>(&plS[qi][l15][32 + lg * 8]));
#pragma unroll
      for (int dc = 0; dc < 4; ++dc) {
        o[qi][dc] = __builtin_amdgcn_mfma_f32_16x16x32_bf16(pa0, vf[0][dc], o[qi][dc], 0, 0, 0);
        o[qi][dc] = __builtin_amdgcn_mfma_f32_16x16x32_bf16(pa1, vf[1][dc], o[qi][dc], 0, 0, 0);
      }
    }
  };

  // main loop, unrolled by 2 for register double-buffered K fragments
  bf16x8 kf0[4][2], kf1[4][2];
  ldk(kf0, 0);
  for (int kt = 0; kt < nktB; kt += 2) {
    bf16x8 vf0[2][4];
    ldv(vf0, kt * 64);
    const int nx1 = (kt + 1 < nktB) ? kt + 1 : nktB - 1;
    ldk(kf1, nx1 * 64);
    processSet(qb0B, qfB, oB, mrB, lrB, pl[0], kf0, vf0, kt * 64);
    if (kt < nktA)
      processSet(qb0A, qfA, oA, mrA, lrA, pl[1], kf0, vf0, kt * 64);
    if (kt + 1 < nktB) {
      bf16x8 vf1[2][4];
      ldv(vf1, (kt + 1) * 64);
      const int nx2 = (kt + 2 < nktB) ? kt + 2 : nktB - 1;
      ldk(kf0, nx2 * 64);
      processSet(qb0B, qfB, oB, mrB, lrB, pl[0], kf1, vf1, (kt + 1) * 64);
      if (kt + 1 < nktA)
        processSet(qb0A, qfA, oA, mrA, lrA, pl[1], kf1, vf1, (kt + 1) * 64);
    }
  }

  auto epi = [&](int qb0, f32x4 (&o)[2][4], float (&lr)[2]) {
#pragma unroll
    for (int qi = 0; qi < 2; ++qi) {
      float linv[4];
#pragma unroll
      for (int r = 0; r < 4; ++r) linv[r] = 1.f / __shfl(lr[qi], lg * 4 + r);
#pragma unroll
      for (int r = 0; r < 4; ++r) {
        const int t = qb0 + qi * 16 + lg * 4 + r;
#pragma unroll
        for (int dc = 0; dc < 4; ++dc)
          Y[(b * TT + t) * CC + h * DD + dc * 16 + l15] = f2b(o[qi][dc][r] * linv[r]);
      }
    }
  };
  epi(qb0B, oB, lrB);
  epi(qb0A, oA, lrA);
}

extern "C" void kernel_launch(void* const* d_in, const int* in_sizes, int n_in,
                              void* d_out, int out_size, void* d_ws, size_t ws_size,
                              hipStream_t stream) {
  const float* x  = (const float*)d_in[0];
  const float* Wq = (const float*)d_in[1];
  const float* bq = (const float*)d_in[2];
  const float* Wk = (const float*)d_in[3];
  const float* bk = (const float*)d_in[4];
  const float* Wv = (const float*)d_in[5];
  const float* bv = (const float*)d_in[6];
  const float* Wo = (const float*)d_in[7];
  const float* bo = (const float*)d_in[8];
  float* out = (float*)d_out;

  unsigned short* ws  = (unsigned short*)d_ws;
  unsigned short* xb  = ws;               // x bf16       [4096][1024]
  unsigned short* wqb = xb  + 4194304;    // Wq bf16
  unsigned short* wkb = wqb + 1048576;
  unsigned short* wvb = wkb + 1048576;
  unsigned short* wob = wvb + 1048576;
  unsigned short* qb  = wob + 1048576;    // Q  [BH][T][D]
  unsigned short* kb  = qb  + 4194304;    // K  [BH][T][D]
  unsigned short* vt  = kb  + 4194304;    // V^T [BH][D][T]
  unsigned short* yb  = xb;               // attn out [B][T][C] — aliases xb (dead after QKV GEMM)

  k_cvt_all<<<8192, 256, 0, stream>>>(x, Wq, Wk, Wv, Wo, ws);

  k_gemm_qkv<<<dim3(32, 24), 256, 0, stream>>>(xb, wqb, wkb, wvb, bq, bk, bv, qb, kb, vt);

  k_attn<<<dim3(32, 32), 64, 0, stream>>>(qb, kb, vt, yb);

  k_gemm_o<<<dim3(32, 16), 256, 0, stream>>>(yb, wob, bo, out);
}

// Round 10
// 205.343 us; speedup vs baseline: 1.0912x; 1.0448x over previous
//
#include <hip/hip_runtime.h>
#include <hip/hip_bf16.h>

// Problem: B=2, T=2048, C=1024, H=16, D=64 causal self-attention fwd.
// All inputs fp32; output fp32. Compute in bf16 MFMA (threshold = 2% of max|ref|).

namespace {

constexpr int TT = 2048;
constexpr int CC = 1024;
constexpr int HH = 16;
constexpr int DD = 64;

using bf16x8 = __attribute__((ext_vector_type(8))) __bf16;
using bf16x4 = __attribute__((ext_vector_type(4))) __bf16;
using f32x4  = __attribute__((ext_vector_type(4))) float;
using us8    = __attribute__((ext_vector_type(8))) unsigned short;

__device__ __forceinline__ unsigned short f2b(float f) {
  unsigned u = __float_as_uint(f);
  u += 0x7fffu + ((u >> 16) & 1u);   // RNE
  return (unsigned short)(u >> 16);
}

// async global->LDS, 16B per lane; LDS dest is wave-uniform base + lane*16
__device__ __forceinline__ void gload16(const void* g, void* l) {
  __builtin_amdgcn_global_load_lds(
      (const __attribute__((address_space(1))) void*)g,
      (__attribute__((address_space(3))) void*)l, 16, 0, 0);
}

#if __has_builtin(__builtin_amdgcn_exp2f)
#define FEXP2 __builtin_amdgcn_exp2f
#else
#define FEXP2 exp2f
#endif

// 1/sqrt(64) * log2(e): softmax computed in exp2 domain
#define SCALE2 0.18033688011112042f

} // namespace

// ---------------- fp32 -> bf16 conversion: all 5 tensors in ONE launch ----------------
__global__ void k_cvt_all(const float* __restrict__ x,
                          const float* __restrict__ wq, const float* __restrict__ wk,
                          const float* __restrict__ wv, const float* __restrict__ wo,
                          unsigned short* __restrict__ dst) {
  const int i = blockIdx.x * 256 + threadIdx.x;   // 0 .. 2097151 float4s
  const float* src; int off;
  if (i < 1048576)      { src = x;  off = i; }
  else if (i < 1310720) { src = wq; off = i - 1048576; }
  else if (i < 1572864) { src = wk; off = i - 1310720; }
  else if (i < 1835008) { src = wv; off = i - 1572864; }
  else                  { src = wo; off = i - 1835008; }
  float4 v = reinterpret_cast<const float4*>(src)[off];
  ushort4 o;
  o.x = f2b(v.x); o.y = f2b(v.y); o.z = f2b(v.z); o.w = f2b(v.w);
  reinterpret_cast<ushort4*>(dst)[i] = o;
}

// ---------------- fused QKV GEMM, 2-deep counted-vmcnt pipeline ----------------
// out[m,n] = sum_k x[m,k]*W[n,k] + bias[n] for W in {Wq,Wk,Wv} selected by blockIdx.y>>3.
// 128x128 tile, BK=32. T4: prefetch 2 tiles deep, wait vmcnt(4) (newer tile keeps
// flying across barriers), raw s_barrier, drain only in the peeled last step.
__global__ __launch_bounds__(256, 3) void k_gemm_qkv(
    const unsigned short* __restrict__ A,    // x bf16 [4096][1024]
    const unsigned short* __restrict__ Wq,
    const unsigned short* __restrict__ Wk,
    const unsigned short* __restrict__ Wv,
    const float* __restrict__ bq,
    const float* __restrict__ bk,
    const float* __restrict__ bv,
    unsigned short* __restrict__ qd,         // [BH][T][D]
    unsigned short* __restrict__ kd,         // [BH][T][D]
    unsigned short* __restrict__ vd)         // [BH][D][T]
{
  __shared__ unsigned short la[2][128 * 32];   // 2 x 8 KB
  __shared__ unsigned short lb[2][128 * 32];
  const int tid = threadIdx.x;
  const int lane = tid & 63;
  const int wid = tid >> 6;
  const int l15 = lane & 15, lg = lane >> 4;
  const int wm = (wid & 1) * 64, wn = (wid >> 1) * 64;
  const int bm = blockIdx.x;
  const int wsel = blockIdx.y >> 3;          // 0=Q 1=K 2=V
  const int bnl = blockIdx.y & 7;

  const unsigned short* W = (wsel == 0) ? Wq : (wsel == 1) ? Wk : Wv;
  const float* bias = (wsel == 0) ? bq : (wsel == 1) ? bk : bv;

  const int srow = lane >> 2;                // 0..15 within segment
  const int sko  = (lane & 3) * 8;           // k-chunk 0/8/16/24

  auto STAGE = [&](int buf, int kt) {        // 4 gloads per wave
#pragma unroll
    for (int s = 0; s < 2; ++s) {
      const int seg = wid * 2 + s;           // 0..7 (16 rows each)
      const int row = seg * 16 + srow;
      gload16(&A[(bm * 128 + row) * CC + kt * 32 + sko], &la[buf][seg * 512]);
      gload16(&W[(bnl * 128 + row) * CC + kt * 32 + sko], &lb[buf][seg * 512]);
    }
  };

  f32x4 acc[4][4];
#pragma unroll
  for (int i = 0; i < 4; ++i)
#pragma unroll
    for (int j = 0; j < 4; ++j) acc[i][j] = f32x4{0.f, 0.f, 0.f, 0.f};

  auto COMPUTE = [&](int buf) {
    bf16x8 af[4], bf[4];
#pragma unroll
    for (int mi = 0; mi < 4; ++mi)
      af[mi] = __builtin_bit_cast(bf16x8,
        *reinterpret_cast<const us8*>(&la[buf][(wm + mi * 16 + l15) * 32 + lg * 8]));
#pragma unroll
    for (int ni = 0; ni < 4; ++ni)
      bf[ni] = __builtin_bit_cast(bf16x8,
        *reinterpret_cast<const us8*>(&lb[buf][(wn + ni * 16 + l15) * 32 + lg * 8]));
#pragma unroll
    for (int mi = 0; mi < 4; ++mi)
#pragma unroll
      for (int ni = 0; ni < 4; ++ni)
        acc[mi][ni] = __builtin_amdgcn_mfma_f32_16x16x32_bf16(af[mi], bf[ni], acc[mi][ni], 0, 0, 0);
  };

  STAGE(0, 0);
  STAGE(1, 1);
  int cur = 0;
  for (int kt = 0; kt < CC / 32 - 1; ++kt) {
    asm volatile("s_waitcnt vmcnt(4)" ::: "memory");   // tile kt landed; kt+1 flying
    __builtin_amdgcn_s_barrier();                       // all waves' kt loads landed
    COMPUTE(cur);
    __builtin_amdgcn_s_barrier();                       // all waves done reading cur
    if (kt < CC / 32 - 2) STAGE(cur, kt + 2);
    cur ^= 1;
  }
  asm volatile("s_waitcnt vmcnt(0)" ::: "memory");      // peeled last step: full drain
  __builtin_amdgcn_s_barrier();
  COMPUTE(cur);

  // epilogue: C/D col = lane&15, row = (lane>>4)*4 + r
#pragma unroll
  for (int ni = 0; ni < 4; ++ni) {
    const int nl = bnl * 128 + wn + ni * 16 + l15;   // 0..1023
    const float bvl = bias[nl];
    const int hh = nl >> 6, d = nl & (DD - 1);
#pragma unroll
    for (int mi = 0; mi < 4; ++mi) {
#pragma unroll
      for (int r = 0; r < 4; ++r) {
        const int m = bm * 128 + wm + mi * 16 + lg * 4 + r;
        const unsigned short bb = f2b(acc[mi][ni][r] + bvl);
        const int b = m >> 11, t = m & (TT - 1);
        if (wsel == 0)
          qd[((b * HH + hh) * TT + t) * DD + d] = bb;
        else if (wsel == 1)
          kd[((b * HH + hh) * TT + t) * DD + d] = bb;
        else
          vd[((b * HH + hh) * DD + d) * TT + t] = bb;
      }
    }
  }
}

// ---------------- output projection GEMM, 2-deep counted-vmcnt ----------------
// 128x64 tile, BK=32, grid (32,16) = 512 blocks -> 2 blocks/CU. 3 gloads/wave/stage.
__global__ __launch_bounds__(256, 2) void k_gemm_o(
    const unsigned short* __restrict__ A,    // y bf16 [4096][1024]
    const unsigned short* __restrict__ W,    // Wo bf16 [1024][1024]
    const float* __restrict__ bias,
    float* __restrict__ out)
{
  __shared__ unsigned short la[2][128 * 32];
  __shared__ unsigned short lb[2][64 * 32];
  const int tid = threadIdx.x;
  const int lane = tid & 63;
  const int wid = tid >> 6;
  const int l15 = lane & 15, lg = lane >> 4;
  const int wm = (wid & 1) * 64, wn = (wid >> 1) * 32;
  const int bm = blockIdx.x, bn = blockIdx.y;

  const int srow = lane >> 2;
  const int sko  = (lane & 3) * 8;

  auto STAGE = [&](int buf, int kt) {        // 3 gloads per wave
#pragma unroll
    for (int s = 0; s < 2; ++s) {
      const int seg = wid * 2 + s;
      gload16(&A[(bm * 128 + seg * 16 + srow) * CC + kt * 32 + sko], &la[buf][seg * 512]);
    }
    gload16(&W[(bn * 64 + wid * 16 + srow) * CC + kt * 32 + sko], &lb[buf][wid * 512]);
  };

  f32x4 acc[4][2];
#pragma unroll
  for (int i = 0; i < 4; ++i)
#pragma unroll
    for (int j = 0; j < 2; ++j) acc[i][j] = f32x4{0.f, 0.f, 0.f, 0.f};

  auto COMPUTE = [&](int buf) {
    bf16x8 af[4], bf[2];
#pragma unroll
    for (int mi = 0; mi < 4; ++mi)
      af[mi] = __builtin_bit_cast(bf16x8,
        *reinterpret_cast<const us8*>(&la[buf][(wm + mi * 16 + l15) * 32 + lg * 8]));
#pragma unroll
    for (int ni = 0; ni < 2; ++ni)
      bf[ni] = __builtin_bit_cast(bf16x8,
        *reinterpret_cast<const us8*>(&lb[buf][(wn + ni * 16 + l15) * 32 + lg * 8]));
#pragma unroll
    for (int mi = 0; mi < 4; ++mi)
#pragma unroll
      for (int ni = 0; ni < 2; ++ni)
        acc[mi][ni] = __builtin_amdgcn_mfma_f32_16x16x32_bf16(af[mi], bf[ni], acc[mi][ni], 0, 0, 0);
  };

  STAGE(0, 0);
  STAGE(1, 1);
  int cur = 0;
  for (int kt = 0; kt < CC / 32 - 1; ++kt) {
    asm volatile("s_waitcnt vmcnt(3)" ::: "memory");
    __builtin_amdgcn_s_barrier();
    COMPUTE(cur);
    __builtin_amdgcn_s_barrier();
    if (kt < CC / 32 - 2) STAGE(cur, kt + 2);
    cur ^= 1;
  }
  asm volatile("s_waitcnt vmcnt(0)" ::: "memory");
  __builtin_amdgcn_s_barrier();
  COMPUTE(cur);

#pragma unroll
  for (int ni = 0; ni < 2; ++ni) {
    const int n = bn * 64 + wn + ni * 16 + l15;
    const float bvl = bias[n];
#pragma unroll
    for (int mi = 0; mi < 4; ++mi)
#pragma unroll
      for (int r = 0; r < 4; ++r) {
        const int m = bm * 128 + wm + mi * 16 + lg * 4 + r;
        out[m * CC + n] = acc[mi][ni][r] + bvl;
      }
  }
}

// ---------------- flash attention (round-7 verified compute; + XCD swizzle) ----------------
// 1 wave/block; each wave owns the q-block PAIR (p, 63-p) -> uniform 33 k-tiles/wave.
// XCD swizzle: all 32 p-blocks of a head run on one XCD -> K/V L2-resident.
__global__ __launch_bounds__(64) void k_attn(
    const unsigned short* __restrict__ Q,   // [BH][T][D] bf16
    const unsigned short* __restrict__ K,   // [BH][T][D] bf16
    const unsigned short* __restrict__ VT,  // [BH][D][T] bf16
    unsigned short* __restrict__ Y)         // [B][T][C] bf16
{
  __shared__ unsigned short pl[2][2][16][80];  // [set][qi][q-row][key], padded rows
  const int lane = threadIdx.x;
  const int l15 = lane & 15, lg = lane >> 4;
  // bijective XCD swizzle (1024 blocks, 1024 % 8 == 0): each XCD gets 128
  // consecutive swz ids = 4 complete heads (all 32 q-pair blocks per head).
  const int wg = blockIdx.x + 32 * blockIdx.y;
  const int swz = (wg & 7) * 128 + (wg >> 3);
  const int p = swz & 31;                  // q-pair index 0..31
  const int bh = swz >> 5;                 // head 0..31
  const int b = bh >> 4, h = bh & 15;
  const int qb0A = p * 32;                 // low q-block
  const int qb0B = (63 - p) * 32;          // high q-block
  const int nktA = (qb0A + 95) >> 6;
  const int nktB = (qb0B + 95) >> 6;       // nktA + nktB == 33 for all p

  const unsigned short* Qh = Q + bh * TT * DD;
  const unsigned short* Kh = K + bh * TT * DD;
  const unsigned short* Vh = VT + bh * DD * TT;

  auto ldq = [&](bf16x8 (&qf)[2][2], int qb0) {
#pragma unroll
    for (int qi = 0; qi < 2; ++qi)
#pragma unroll
      for (int kk = 0; kk < 2; ++kk)
        qf[qi][kk] = __builtin_bit_cast(bf16x8,
          *reinterpret_cast<const us8*>(&Qh[(qb0 + qi * 16 + l15) * DD + kk * 32 + lg * 8]));
  };
  auto ldk = [&](bf16x8 (&kf)[4][2], int kb) {
#pragma unroll
    for (int f = 0; f < 4; ++f)
#pragma unroll
      for (int kk = 0; kk < 2; ++kk)
        kf[f][kk] = __builtin_bit_cast(bf16x8,
          *reinterpret_cast<const us8*>(&Kh[(kb + f * 16 + l15) * DD + kk * 32 + lg * 8]));
  };
  auto ldv = [&](bf16x8 (&vf)[2][4], int kb) {
#pragma unroll
    for (int kk = 0; kk < 2; ++kk)
#pragma unroll
      for (int dc = 0; dc < 4; ++dc)
        vf[kk][dc] = __builtin_bit_cast(bf16x8,
          *reinterpret_cast<const us8*>(&Vh[(dc * 16 + l15) * TT + kb + kk * 32 + lg * 8]));
  };

  bf16x8 qfA[2][2], qfB[2][2];
  ldq(qfA, qb0A); ldq(qfB, qb0B);

  f32x4 oA[2][4], oB[2][4];
  float mrA[2], lrA[2], mrB[2], lrB[2];
#pragma unroll
  for (int qi = 0; qi < 2; ++qi) {
    mrA[qi] = -INFINITY; lrA[qi] = 0.f;
    mrB[qi] = -INFINITY; lrB[qi] = 0.f;
#pragma unroll
    for (int dc = 0; dc < 4; ++dc) {
      oA[qi][dc] = f32x4{0.f, 0.f, 0.f, 0.f};
      oB[qi][dc] = f32x4{0.f, 0.f, 0.f, 0.f};
    }
  }

  auto processSet = [&](const int qb0, const bf16x8 (&qf)[2][2], f32x4 (&o)[2][4],
                        float (&mr)[2], float (&lr)[2],
                        unsigned short (&plS)[2][16][80],
                        const bf16x8 (&kf)[4][2], const bf16x8 (&vf)[2][4],
                        const int kbase) {
    // S^T = K Q^T : C[row=key=lg*4+r][col=q=l15]
    f32x4 s[2][4];
#pragma unroll
    for (int qi = 0; qi < 2; ++qi)
#pragma unroll
      for (int f = 0; f < 4; ++f) {
        f32x4 t0 = __builtin_amdgcn_mfma_f32_16x16x32_bf16(kf[f][0], qf[qi][0],
                                                           f32x4{0.f,0.f,0.f,0.f}, 0, 0, 0);
        s[qi][f] = __builtin_amdgcn_mfma_f32_16x16x32_bf16(kf[f][1], qf[qi][1], t0, 0, 0, 0);
      }
    const bool needMask = (kbase + 63 > qb0);  // wave-uniform
#pragma unroll
    for (int qi = 0; qi < 2; ++qi) {
      const int qg = qb0 + qi * 16 + l15;
      float sv[4][4];
      float mt = -INFINITY;
#pragma unroll
      for (int f = 0; f < 4; ++f)
#pragma unroll
        for (int r = 0; r < 4; ++r) {
          float v = s[qi][f][r] * SCALE2;
          if (needMask) v = (kbase + f * 16 + lg * 4 + r <= qg) ? v : -INFINITY;
          sv[f][r] = v;
          mt = fmaxf(mt, v);
        }
      mt = fmaxf(mt, __shfl_xor(mt, 16));
      mt = fmaxf(mt, __shfl_xor(mt, 32));
      const float mn = fmaxf(mr[qi], mt);
      const float al = FEXP2(mr[qi] - mn);   // first tile: exp2(-inf)=0
      mr[qi] = mn;
      float rs = 0.f;
#pragma unroll
      for (int f = 0; f < 4; ++f) {
        const float p0 = FEXP2(sv[f][0] - mn), p1 = FEXP2(sv[f][1] - mn);
        const float p2 = FEXP2(sv[f][2] - mn), p3 = FEXP2(sv[f][3] - mn);
        rs += (p0 + p1) + (p2 + p3);
        bf16x4 pk;
        pk[0] = (__bf16)p0; pk[1] = (__bf16)p1; pk[2] = (__bf16)p2; pk[3] = (__bf16)p3;
        *reinterpret_cast<bf16x4*>(&plS[qi][l15][f * 16 + lg * 4]) = pk;  // keys contiguous
      }
      rs += __shfl_xor(rs, 16);
      rs += __shfl_xor(rs, 32);
      lr[qi] = lr[qi] * al + rs;
      float alr[4];
#pragma unroll
      for (int r = 0; r < 4; ++r) alr[r] = __shfl(al, lg * 4 + r);  // q remap for C-layout
#pragma unroll
      for (int dc = 0; dc < 4; ++dc)
#pragma unroll
        for (int r = 0; r < 4; ++r) o[qi][dc][r] *= alr[r];
    }
    asm volatile("s_waitcnt lgkmcnt(0)" ::: "memory");
    __builtin_amdgcn_sched_barrier(0);
    // PV: A = P[row=q][k=key] from LDS, B = V^T fragments
#pragma unroll
    for (int qi = 0; qi < 2; ++qi) {
      const bf16x8 pa0 = __builtin_bit_cast(bf16x8,
        *reinterpret_cast<const us8*>(&plS[qi][l15][lg * 8]));
      const bf16x8 pa1 = __builtin_bit_cast(bf16x8,
        *reinterpret_cast<const us8*>(&plS[qi][l15][32 + lg * 8]));
#pragma unroll
      for (int dc = 0; dc < 4; ++dc) {
        o[qi][dc] = __builtin_amdgcn_mfma_f32_16x16x32_bf16(pa0, vf[0][dc], o[qi][dc], 0, 0, 0);
        o[qi][dc] = __builtin_amdgcn_mfma_f32_16x16x32_bf16(pa1, vf[1][dc], o[qi][dc], 0, 0, 0);
      }
    }
  };

  // main loop, unrolled by 2 for register double-buffered K fragments
  bf16x8 kf0[4][2], kf1[4][2];
  ldk(kf0, 0);
  for (int kt = 0; kt < nktB; kt += 2) {
    bf16x8 vf0[2][4];
    ldv(vf0, kt * 64);
    const int nx1 = (kt + 1 < nktB) ? kt + 1 : nktB - 1;
    ldk(kf1, nx1 * 64);
    processSet(qb0B, qfB, oB, mrB, lrB, pl[0], kf0, vf0, kt * 64);
    if (kt < nktA)
      processSet(qb0A, qfA, oA, mrA, lrA, pl[1], kf0, vf0, kt * 64);
    if (kt + 1 < nktB) {
      bf16x8 vf1[2][4];
      ldv(vf1, (kt + 1) * 64);
      const int nx2 = (kt + 2 < nktB) ? kt + 2 : nktB - 1;
      ldk(kf0, nx2 * 64);
      processSet(qb0B, qfB, oB, mrB, lrB, pl[0], kf1, vf1, (kt + 1) * 64);
      if (kt + 1 < nktA)
        processSet(qb0A, qfA, oA, mrA, lrA, pl[1], kf1, vf1, (kt + 1) * 64);
    }
  }

  auto epi = [&](int qb0, f32x4 (&o)[2][4], float (&lr)[2]) {
#pragma unroll
    for (int qi = 0; qi < 2; ++qi) {
      float linv[4];
#pragma unroll
      for (int r = 0; r < 4; ++r) linv[r] = 1.f / __shfl(lr[qi], lg * 4 + r);
#pragma unroll
      for (int r = 0; r < 4; ++r) {
        const int t = qb0 + qi * 16 + lg * 4 + r;
#pragma unroll
        for (int dc = 0; dc < 4; ++dc)
          Y[(b * TT + t) * CC + h * DD + dc * 16 + l15] = f2b(o[qi][dc][r] * linv[r]);
      }
    }
  };
  epi(qb0B, oB, lrB);
  epi(qb0A, oA, lrA);
}

extern "C" void kernel_launch(void* const* d_in, const int* in_sizes, int n_in,
                              void* d_out, int out_size, void* d_ws, size_t ws_size,
                              hipStream_t stream) {
  const float* x  = (const float*)d_in[0];
  const float* Wq = (const float*)d_in[1];
  const float* bq = (const float*)d_in[2];
  const float* Wk = (const float*)d_in[3];
  const float* bk = (const float*)d_in[4];
  const float* Wv = (const float*)d_in[5];
  const float* bv = (const float*)d_in[6];
  const float* Wo = (const float*)d_in[7];
  const float* bo = (const float*)d_in[8];
  float* out = (float*)d_out;

  unsigned short* ws  = (unsigned short*)d_ws;
  unsigned short* xb  = ws;               // x bf16       [4096][1024]
  unsigned short* wqb = xb  + 4194304;    // Wq bf16
  unsigned short* wkb = wqb + 1048576;
  unsigned short* wvb = wkb + 1048576;
  unsigned short* wob = wvb + 1048576;
  unsigned short* qb  = wob + 1048576;    // Q  [BH][T][D]
  unsigned short* kb  = qb  + 4194304;    // K  [BH][T][D]
  unsigned short* vt  = kb  + 4194304;    // V^T [BH][D][T]
  unsigned short* yb  = xb;               // attn out [B][T][C] — aliases xb (dead after QKV GEMM)

  k_cvt_all<<<8192, 256, 0, stream>>>(x, Wq, Wk, Wv, Wo, ws);

  k_gemm_qkv<<<dim3(32, 24), 256, 0, stream>>>(xb, wqb, wkb, wvb, bq, bk, bv, qb, kb, vt);

  k_attn<<<dim3(32, 32), 64, 0, stream>>>(qb, kb, vt, yb);

  k_gemm_o<<<dim3(32, 16), 256, 0, stream>>>(yb, wob, bo, out);
}